// Round 6
// baseline (1614.956 us; speedup 1.0000x reference)
//
#include <hip/hip_runtime.h>
#include <math.h>

// global_powermean_pooling, P = 2.0
//   out[g, d] = sqrt( mean_{n : batch[n]==g} x[n, d]^2 ),  empty segment -> 0
// x: [N, 128] fp32, batch: [N] int32 sorted ascending in [0, G)
//
// R7 — orchestration squeeze: 4 kernels -> 2, CHUNK 64->128, backward sweep.
// Evidence ledger (rounds R1-R6):
//   * Harness ws poison fill: 2GB @ ~6.4TB/s ≈ 320us, unconditional, inside
//     the timed window. Fixed floor term.
//   * Pool's mandatory 512MB cold read runs ~1.75 TB/s in the timed window
//     (dirty-MALL / cold-allocate state after the fill) vs 6.4 TB/s warm
//     (R5 pass-2 A/B: +80.5us marginal). Four structures (streams / split+NT /
//     fwd sweep / NT-asm sweep) all pinned ~290-315us; sc0|sc1|nt bought 22us.
//     No further in-kernel mechanism found for the state tax.
//   * This round removes launch/dispatch overhead: prologue fuses
//     seg_offsets + zero(out) + zero(contrib); pool fuses finalize via
//     per-graph contribution counting (last contributor does sqrt in-place).
//     Chunk order reversed (free experiment vs the eviction stream).

#define D_FEAT 128
#define DV 32             // float4 per row
#define SWEEP_GRID 2048   // 8 blocks/CU
#define CHUNK 128         // rows per sweep chunk (64 KB)
#define CHUNK_SHIFT 7

typedef float f32x4 __attribute__((ext_vector_type(4)));

// ---- non-allocating 16B load helpers (R6, -22us) -------------------------
__device__ __forceinline__ void nt_load4x(
    const f32x4* p0, const f32x4* p1, const f32x4* p2, const f32x4* p3,
    f32x4& v0, f32x4& v1, f32x4& v2, f32x4& v3)
{
    asm volatile(
        "global_load_dwordx4 %0, %4, off sc0 sc1 nt\n\t"
        "global_load_dwordx4 %1, %5, off sc0 sc1 nt\n\t"
        "global_load_dwordx4 %2, %6, off sc0 sc1 nt\n\t"
        "global_load_dwordx4 %3, %7, off sc0 sc1 nt\n\t"
        "s_waitcnt vmcnt(0)"
        : "=&v"(v0), "=&v"(v1), "=&v"(v2), "=&v"(v3)
        : "v"(p0), "v"(p1), "v"(p2), "v"(p3));
}

__device__ __forceinline__ f32x4 nt_load1(const f32x4* p)
{
    f32x4 v;
    asm volatile(
        "global_load_dwordx4 %0, %1, off sc0 sc1 nt\n\t"
        "s_waitcnt vmcnt(0)"
        : "=&v"(v) : "v"(p));
    return v;
}

// ---- Kernel 1: prologue = seg_offsets + zero(out) + zero(contrib) --------
__global__ __launch_bounds__(256) void prologue_kernel(
    const int* __restrict__ batch, int* __restrict__ off,
    f32x4* __restrict__ out4, int* __restrict__ contrib, int N, int G)
{
    const int i = blockIdx.x * 256 + threadIdx.x;
    if (i < G * DV) out4[i] = (f32x4)0.f;     // 131072 threads zero out
    if (i < G)      contrib[i] = 0;           // 4096 threads zero counters
    if (i >= N) return;
    const int cur = batch[i];
    if (i == 0) {
        for (int g = 0; g <= cur; ++g) off[g] = 0;
    } else {
        const int prev = batch[i - 1];
        for (int g = prev + 1; g <= cur; ++g) off[g] = i;
    }
    if (i == N - 1) {
        for (int g = cur + 1; g <= G; ++g) off[g] = N;
    }
}

// ---- Kernel 2: backward sweep pool + fused finalize ----------------------
// Grid-strides chunks in REVERSE order (front starts at x tail). Per run:
// NT-load + square-accumulate, LDS reduce 8 lanes -> 1, 128 atomicAdds into
// out[g,:], then the per-graph contribution counter; the block completing the
// known total (#chunks overlapping g, from off[]) finalizes g in-place with
// sqrt(sum/count). Release: threadfence before counter-inc; acquire:
// threadfence + atomic-read after winning.
__global__ __launch_bounds__(256) void global_powermean_pooling_44126493999223_kernel(
    const f32x4* __restrict__ x4,
    const int*   __restrict__ batch,
    const int*   __restrict__ off,
    int*         __restrict__ contrib,
    float*       __restrict__ out,
    int N)
{
    const int tid  = threadIdx.x;
    const int fg   = tid & 31;   // float4 index within 128-wide row
    const int lane = tid >> 5;   // node-lane 0..7

    __shared__ f32x4 red[256];
    __shared__ int s_fin, s_cnt;

    const int nchunks = (N + CHUNK - 1) / CHUNK;
    const int c0 = blockIdx.x + ((nchunks - 1 - blockIdx.x) / SWEEP_GRID) * SWEEP_GRID;
    for (int c = c0; c >= 0; c -= SWEEP_GRID) {
        const int rs = c * CHUNK;
        const int re = (rs + CHUNK < N) ? rs + CHUNK : N;
        int cur = rs;
        int g = batch[rs];                 // block-uniform broadcast load
        while (cur < re) {
            const int ge = off[g + 1];     // global end of graph g
            const int run_end = (ge < re) ? ge : re;

            f32x4 a0 = (f32x4)0.f, a1 = (f32x4)0.f, a2 = (f32x4)0.f, a3 = (f32x4)0.f;
            int r = cur + lane;
            for (; r + 24 < run_end; r += 32) {
                const f32x4* p0 = x4 + (size_t)(r     ) * DV + fg;
                const f32x4* p1 = x4 + (size_t)(r +  8) * DV + fg;
                const f32x4* p2 = x4 + (size_t)(r + 16) * DV + fg;
                const f32x4* p3 = x4 + (size_t)(r + 24) * DV + fg;
                f32x4 v0, v1, v2, v3;
                nt_load4x(p0, p1, p2, p3, v0, v1, v2, v3);
                a0 += v0 * v0; a1 += v1 * v1; a2 += v2 * v2; a3 += v3 * v3;
            }
            for (; r < run_end; r += 8) {
                f32x4 v = nt_load1(x4 + (size_t)r * DV + fg);
                a0 += v * v;
            }
            a0 += a1; a2 += a3; a0 += a2;

            red[tid] = a0;
            __syncthreads();
            if (lane < 4) red[tid] += red[tid + 128];
            __syncthreads();
            if (lane < 2) red[tid] += red[tid + 64];
            __syncthreads();
            if (lane == 0) {
                f32x4 s = red[tid] + red[tid + 32];
                float* dst = out + (size_t)g * D_FEAT + fg * 4;
                atomicAdd(dst + 0, s[0]);
                atomicAdd(dst + 1, s[1]);
                atomicAdd(dst + 2, s[2]);
                atomicAdd(dst + 3, s[3]);
                __threadfence();           // release our 4 adds
            }
            __syncthreads();               // all 128 adds released
            if (tid == 0) {
                const int gs    = off[g];
                const int total = ((ge - 1) >> CHUNK_SHIFT) - (gs >> CHUNK_SHIFT) + 1;
                const int old   = atomicAdd(&contrib[g], 1);
                s_fin = (old == total - 1) ? g : -1;
                s_cnt = ge - gs;
            }
            __syncthreads();
            if (s_fin >= 0) {
                if (tid < D_FEAT) {
                    __threadfence();       // acquire all contributors' adds
                    float* p = out + (size_t)s_fin * D_FEAT + tid;
                    const float v = atomicAdd(p, 0.0f);   // L2-coherent read
                    *p = sqrtf(v / (float)s_cnt);         // we are last: safe
                }
            }
            __syncthreads();               // red / s_fin reused next run
            cur = run_end;
            if (cur < re) g = batch[cur];  // uniform
        }
    }
}

extern "C" void kernel_launch(void* const* d_in, const int* in_sizes, int n_in,
                              void* d_out, int out_size, void* d_ws, size_t ws_size,
                              hipStream_t stream) {
    const float* x     = (const float*)d_in[0];
    const int*   batch = (const int*)d_in[1];
    float*       out   = (float*)d_out;

    const int N = in_sizes[1];           // 1,000,000 nodes
    const int G = out_size / D_FEAT;     // 4096 graphs

    int* off     = (int*)d_ws;                       // (G+1) ints
    int* contrib = (int*)((char*)d_ws + (64 << 10)); // G ints at +64KB

    prologue_kernel<<<(N + 255) / 256, 256, 0, stream>>>(
        batch, off, (f32x4*)out, contrib, N, G);
    global_powermean_pooling_44126493999223_kernel
        <<<SWEEP_GRID, 256, 0, stream>>>((const f32x4*)x, batch, off, contrib, out, N);
}